// Round 2
// baseline (864.194 us; speedup 1.0000x reference)
//
#include <hip/hip_runtime.h>

// Problem constants
#define NB 512
#define NTOK 128
#define NC 384
#define NH 6
#define ND 64

typedef short s16x8 __attribute__((ext_vector_type(8)));
typedef float f32x4 __attribute__((ext_vector_type(4)));

#define MFMA16(a, b, c) __builtin_amdgcn_mfma_f32_16x16x32_bf16((a), (b), (c), 0, 0, 0)

static __device__ __forceinline__ unsigned short f2bf(float f) {
  unsigned int u = __builtin_bit_cast(unsigned int, f);
  u = (u + 0x7FFFu + ((u >> 16) & 1u)) >> 16;   // RNE truncate to bf16
  return (unsigned short)u;
}

static __device__ __forceinline__ uint2 pack4(float a, float b, float c, float d) {
  union { unsigned short h[4]; uint2 u; } t;
  t.h[0] = f2bf(a); t.h[1] = f2bf(b); t.h[2] = f2bf(c); t.h[3] = f2bf(d);
  return t.u;
}

// ---------------- kernel 0: convert + transpose weights to bf16 ----------------
// wqkvT layout: [m][h][d][c]  (m in {q,k,v}) -> B-fragment reads are 8 contiguous c
// wpT   layout: [c_out][j]                   -> B-fragment reads are 8 contiguous j
__global__ __launch_bounds__(256) void convert_weights(
    const float* __restrict__ Wq, const float* __restrict__ Wk,
    const float* __restrict__ Wv, const float* __restrict__ Wp,
    unsigned short* __restrict__ wqkvT, unsigned short* __restrict__ wpT) {
  int idx = blockIdx.x * 256 + threadIdx.x;
  const int NQKV = 3 * NH * ND * NC;  // 442368
  if (idx < NQKV) {
    int c = idx % NC;
    int d = (idx / NC) % ND;
    int h = (idx / (NC * ND)) % NH;
    int m = idx / (NC * ND * NH);
    const float* W = (m == 0) ? Wq : (m == 1) ? Wk : Wv;
    wqkvT[idx] = f2bf(W[(h * NC + c) * ND + d]);
  } else {
    int j = idx - NQKV;               // 0 .. NC*NC-1
    int cc = j / NC, r = j % NC;      // wpT[cc][r] = Wp[r][cc]
    wpT[j] = f2bf(Wp[r * NC + cc]);
  }
}

// ---------------- kernel 1: fused QKV + causal softmax + PV per (b,h) ----------------
// 512 threads = 8 waves; each wave owns 16 q-rows (r0 = wid*16).
// LDS layout (exactly 81920 B -> 2 blocks/CU -> 16 waves/CU):
//   union buf1 (46080 B): phase1 {xs[128][72], w[3][64][72]} -> phase2 qs[128][72]
//                         -> phase3 pB[128][136]
//   ks[128][72]  (18432 B)   vts[64][136] (17408 B, V^T: rows d, cols s)
// Strides 72/136 shorts = 144/272 B: 16B-aligned rows, uniform bank coverage
// for all ds_read_b128 fragment reads (8 touches/bank = theoretical min).
__global__ __launch_bounds__(512, 4) void attn_fused(
    const float* __restrict__ x, const unsigned short* __restrict__ wqkvT,
    unsigned short* __restrict__ O) {
  const int b = blockIdx.x / NH;      // b-major: 6 heads of b dispatch adjacently
  const int h = blockIdx.x % NH;      //          -> x[b] fetched once per window
  const int tid = threadIdx.x;
  const int lane = tid & 63;
  const int l15 = lane & 15;
  const int lg = lane >> 4;           // 0..3
  const int wid = tid >> 6;           // 0..7
  const int r0 = wid * 16;            // wave's 16 q-rows

  __shared__ __align__(16) union {
    struct { unsigned short xs[128][72]; unsigned short w[3][64][72]; } s1;
    struct { unsigned short qs[128][72]; } s2;
    struct { unsigned short pB[128][136]; } s3;   // P row-major [q][s]
  } u;
  __shared__ __align__(16) unsigned short ks[128][72];
  __shared__ __align__(16) unsigned short vts[64][136];

  f32x4 accq[4], acck[4], accv[4];
#pragma unroll
  for (int j = 0; j < 4; ++j) {
    accq[j] = f32x4{0.f, 0.f, 0.f, 0.f};
    acck[j] = f32x4{0.f, 0.f, 0.f, 0.f};
    accv[j] = f32x4{0.f, 0.f, 0.f, 0.f};
  }

  // staging assignments (K-chunk = 64)
  const float* xb = x + (size_t)b * (NTOK * NC);
  const int xrow = tid >> 2;                 // 0..127
  const int xcc = (tid & 3) * 16;            // 16 floats each
  const float* xg = xb + xrow * NC + xcc;
  const int wrow = (tid >> 3) & 63;          // 0..63
  const int wcc = (tid & 7) * 8;             // 8 shorts each
  const unsigned short* wg = wqkvT + ((size_t)h * ND + wrow) * NC + wcc;
  const int WM = NH * ND * NC;               // 147456, m-stride

  float4 xa0, xa1, xa2, xa3;
  s16x8 wa0, wa1, wa2;
  xa0 = *(const float4*)(xg + 0);  xa1 = *(const float4*)(xg + 4);
  xa2 = *(const float4*)(xg + 8);  xa3 = *(const float4*)(xg + 12);
  wa0 = *(const s16x8*)(wg);
  wa1 = *(const s16x8*)(wg + WM);
  wa2 = *(const s16x8*)(wg + 2 * WM);

  // ---- phase 1: Q,K,V = x @ W, 6 iterations of K=64 ----
  for (int kc = 0; kc < 6; ++kc) {
    __syncthreads();
    union { unsigned short hh[8]; s16x8 v; } t0, t1;
    t0.hh[0] = f2bf(xa0.x); t0.hh[1] = f2bf(xa0.y); t0.hh[2] = f2bf(xa0.z); t0.hh[3] = f2bf(xa0.w);
    t0.hh[4] = f2bf(xa1.x); t0.hh[5] = f2bf(xa1.y); t0.hh[6] = f2bf(xa1.z); t0.hh[7] = f2bf(xa1.w);
    t1.hh[0] = f2bf(xa2.x); t1.hh[1] = f2bf(xa2.y); t1.hh[2] = f2bf(xa2.z); t1.hh[3] = f2bf(xa2.w);
    t1.hh[4] = f2bf(xa3.x); t1.hh[5] = f2bf(xa3.y); t1.hh[6] = f2bf(xa3.z); t1.hh[7] = f2bf(xa3.w);
    *(s16x8*)&u.s1.xs[xrow][xcc] = t0.v;
    *(s16x8*)&u.s1.xs[xrow][xcc + 8] = t1.v;
    *(s16x8*)&u.s1.w[0][wrow][wcc] = wa0;
    *(s16x8*)&u.s1.w[1][wrow][wcc] = wa1;
    *(s16x8*)&u.s1.w[2][wrow][wcc] = wa2;
    __syncthreads();
    if (kc < 5) {                       // T14: issue next chunk before compute
      xg += 64; wg += 64;
      xa0 = *(const float4*)(xg + 0);  xa1 = *(const float4*)(xg + 4);
      xa2 = *(const float4*)(xg + 8);  xa3 = *(const float4*)(xg + 12);
      wa0 = *(const s16x8*)(wg);
      wa1 = *(const s16x8*)(wg + WM);
      wa2 = *(const s16x8*)(wg + 2 * WM);
    }
#pragma unroll
    for (int kd = 0; kd < 2; ++kd) {
      s16x8 a = *(const s16x8*)&u.s1.xs[r0 + l15][kd * 32 + lg * 8];
#pragma unroll
      for (int nt = 0; nt < 4; ++nt) {
        s16x8 bq = *(const s16x8*)&u.s1.w[0][nt * 16 + l15][kd * 32 + lg * 8];
        accq[nt] = MFMA16(a, bq, accq[nt]);
        s16x8 bk = *(const s16x8*)&u.s1.w[1][nt * 16 + l15][kd * 32 + lg * 8];
        acck[nt] = MFMA16(a, bk, acck[nt]);
        s16x8 bv = *(const s16x8*)&u.s1.w[2][nt * 16 + l15][kd * 32 + lg * 8];
        accv[nt] = MFMA16(a, bv, accv[nt]);
      }
    }
  }

  // ---- write Q (scaled), K row-major; V^T packed ----
  __syncthreads();
#pragma unroll
  for (int nt = 0; nt < 4; ++nt) {
    int col = nt * 16 + l15;
#pragma unroll
    for (int r = 0; r < 4; ++r) {
      int row = r0 + 4 * lg + r;
      u.s2.qs[row][col] = f2bf(accq[nt][r] * 0.125f);
      ks[row][col] = f2bf(acck[nt][r]);
    }
    *(uint2*)&vts[col][r0 + 4 * lg] =
        pack4(accv[nt][0], accv[nt][1], accv[nt][2], accv[nt][3]);
  }
  __syncthreads();

  // ---- phase 2: S^T = K @ Q^T (swapped operands -> lane-local score rows) ----
  f32x4 sacc[8];
#pragma unroll
  for (int j = 0; j < 8; ++j) sacc[j] = f32x4{0.f, 0.f, 0.f, 0.f};

#pragma unroll
  for (int kd = 0; kd < 2; ++kd) {
    s16x8 bq = *(const s16x8*)&u.s2.qs[r0 + l15][kd * 32 + lg * 8];
#pragma unroll
    for (int nt = 0; nt < 8; ++nt) {
      if (nt <= wid) {                  // causal tile skip (wave-uniform)
        s16x8 ak = *(const s16x8*)&ks[nt * 16 + l15][kd * 32 + lg * 8];
        sacc[nt] = MFMA16(ak, bq, sacc[nt]);
      }
    }
  }

  // in-lane softmax for q = r0 + l15; s = 16*nt + 4*lg + r
  const int q = r0 + l15;
  float mx = -1e30f;
#pragma unroll
  for (int nt = 0; nt < 8; ++nt) {
    if (nt <= wid) {
#pragma unroll
      for (int r = 0; r < 4; ++r) {
        int s = nt * 16 + 4 * lg + r;
        float v = (s <= q) ? sacc[nt][r] : -1e30f;
        sacc[nt][r] = v;
        mx = fmaxf(mx, v);
      }
    }
  }
  mx = fmaxf(mx, __shfl_xor(mx, 16, 64));
  mx = fmaxf(mx, __shfl_xor(mx, 32, 64));
  float sm = 0.f;
#pragma unroll
  for (int nt = 0; nt < 8; ++nt) {
    if (nt <= wid) {
#pragma unroll
      for (int r = 0; r < 4; ++r) {
        float e = __expf(sacc[nt][r] - mx);
        sacc[nt][r] = e;
        sm += e;
      }
    }
  }
  sm += __shfl_xor(sm, 16, 64);
  sm += __shfl_xor(sm, 32, 64);
  float inv = 1.f / sm;

  // ---- stage P row-major [q][s] (overlays qs after barrier) ----
  __syncthreads();
#pragma unroll
  for (int nt = 0; nt < 8; ++nt) {
    uint2 pv;
    if (nt <= wid)
      pv = pack4(sacc[nt][0] * inv, sacc[nt][1] * inv, sacc[nt][2] * inv, sacc[nt][3] * inv);
    else { pv.x = 0u; pv.y = 0u; }
    *(uint2*)&u.s3.pB[r0 + l15][nt * 16 + 4 * lg] = pv;
  }
  __syncthreads();

  // ---- phase 3: O^T = V^T @ P^T (A = vts, B = pB rows of own wave) ----
  f32x4 oacc[4];
#pragma unroll
  for (int j = 0; j < 4; ++j) oacc[j] = f32x4{0.f, 0.f, 0.f, 0.f};
#pragma unroll
  for (int kd = 0; kd < 4; ++kd) {
    if (kd * 32 <= r0 + 15) {           // s-tiles beyond q_max are all-zero P
      s16x8 bp = *(const s16x8*)&u.s3.pB[r0 + l15][kd * 32 + lg * 8];
#pragma unroll
      for (int dt = 0; dt < 4; ++dt) {
        s16x8 av = *(const s16x8*)&vts[dt * 16 + l15][kd * 32 + lg * 8];
        oacc[dt] = MFMA16(av, bp, oacc[dt]);
      }
    }
  }

  // epilogue: lane holds O[q][d], d = 16*dt + 4*lg + r (consecutive r -> uint2)
  unsigned short* Op = O + ((size_t)(b * NTOK) + r0 + l15) * (NH * ND) + h * ND;
#pragma unroll
  for (int dt = 0; dt < 4; ++dt)
    *(uint2*)&Op[dt * 16 + 4 * lg] =
        pack4(oacc[dt][0], oacc[dt][1], oacc[dt][2], oacc[dt][3]);
}

// ---------------- kernel 2: out = O @ Wp + bp  (M=65536, N=384, K=384) ----------------
__global__ __launch_bounds__(256) void proj_gemm(
    const unsigned short* __restrict__ O, const unsigned short* __restrict__ wpT,
    const float* __restrict__ bp, float* __restrict__ out) {
  const int ntile = blockIdx.x >> 9;   // 0..2
  const int mtile = blockIdx.x & 511;
  const int m0 = mtile * 128, n0 = ntile * 128;
  const int tid = threadIdx.x;
  const int lane = tid & 63;
  const int l15 = lane & 15, lg = lane >> 4;
  const int r0 = (tid >> 6) * 32;

  __shared__ __align__(16) unsigned short as_[128][40];
  __shared__ __align__(16) unsigned short bs_[128][40];

  f32x4 acc[2][8];
#pragma unroll
  for (int i = 0; i < 2; ++i)
#pragma unroll
    for (int j = 0; j < 8; ++j) acc[i][j] = f32x4{0.f, 0.f, 0.f, 0.f};

  const int sr = tid >> 2, sc = (tid & 3) * 8;
  const unsigned short* ag = O + (size_t)(m0 + sr) * NC + sc;
  const unsigned short* bg = wpT + (size_t)(n0 + sr) * NC + sc;
  s16x8 ar0 = *(const s16x8*)ag;
  s16x8 ar1 = *(const s16x8*)(ag + (size_t)64 * NC);
  s16x8 br0 = *(const s16x8*)bg;
  s16x8 br1 = *(const s16x8*)(bg + (size_t)64 * NC);

  for (int kc = 0; kc < 12; ++kc) {
    __syncthreads();
    *(s16x8*)&as_[sr][sc] = ar0;  *(s16x8*)&as_[sr + 64][sc] = ar1;
    *(s16x8*)&bs_[sr][sc] = br0;  *(s16x8*)&bs_[sr + 64][sc] = br1;
    __syncthreads();
    if (kc < 11) {                      // T14 prefetch
      ag += 32; bg += 32;
      ar0 = *(const s16x8*)ag;  ar1 = *(const s16x8*)(ag + (size_t)64 * NC);
      br0 = *(const s16x8*)bg;  br1 = *(const s16x8*)(bg + (size_t)64 * NC);
    }
    s16x8 a0 = *(const s16x8*)&as_[r0 + l15][lg * 8];
    s16x8 a1 = *(const s16x8*)&as_[r0 + 16 + l15][lg * 8];
#pragma unroll
    for (int nt = 0; nt < 8; ++nt) {
      s16x8 bb = *(const s16x8*)&bs_[nt * 16 + l15][lg * 8];
      acc[0][nt] = MFMA16(a0, bb, acc[0][nt]);
      acc[1][nt] = MFMA16(a1, bb, acc[1][nt]);
    }
  }
#pragma unroll
  for (int mt = 0; mt < 2; ++mt)
#pragma unroll
    for (int nt = 0; nt < 8; ++nt) {
      int trow = m0 + r0 + 16 * mt + 4 * lg;
      int col = n0 + nt * 16 + l15;
      float bias = bp[col];
#pragma unroll
      for (int r = 0; r < 4; ++r)
        out[(size_t)(trow + r) * NC + col] = acc[mt][nt][r] + bias;
    }
}

// ---------------- launch ----------------
extern "C" void kernel_launch(void* const* d_in, const int* in_sizes, int n_in,
                              void* d_out, int out_size, void* d_ws, size_t ws_size,
                              hipStream_t stream) {
  const float* x  = (const float*)d_in[0];
  const float* Wq = (const float*)d_in[1];
  const float* Wk = (const float*)d_in[2];
  const float* Wv = (const float*)d_in[3];
  const float* Wp = (const float*)d_in[4];
  const float* bp = (const float*)d_in[5];
  float* out = (float*)d_out;

  char* ws = (char*)d_ws;
  // ws layout: O bf16 [65536][384] @0 (50,331,648 B); wqkvT @50,331,648 (884,736 B);
  //            wpT @51,216,384 (294,912 B). Total ~49.2 MiB.
  unsigned short* O     = (unsigned short*)(ws);
  unsigned short* wqkvT = (unsigned short*)(ws + 50331648);
  unsigned short* wpT   = (unsigned short*)(ws + 51216384);

  convert_weights<<<2304, 256, 0, stream>>>(Wq, Wk, Wv, Wp, wqkvT, wpT);
  attn_fused<<<NB * NH, 512, 0, stream>>>(x, wqkvT, O);
  proj_gemm<<<3 * 512, 256, 0, stream>>>(O, wpT, bp, out);
}

// Round 4
// 436.796 us; speedup vs baseline: 1.9785x; 1.9785x over previous
//
#include <hip/hip_runtime.h>

// Problem constants
#define NB 512
#define NTOK 128
#define NC 384
#define NH 6
#define ND 64

typedef short s16x8 __attribute__((ext_vector_type(8)));
typedef float f32x4 __attribute__((ext_vector_type(4)));

#define MFMA16(a, b, c) __builtin_amdgcn_mfma_f32_16x16x32_bf16((a), (b), (c), 0, 0, 0)

static __device__ __forceinline__ unsigned short f2bf(float f) {
  unsigned int u = __builtin_bit_cast(unsigned int, f);
  u = (u + 0x7FFFu + ((u >> 16) & 1u)) >> 16;   // RNE truncate to bf16
  return (unsigned short)u;
}

static __device__ __forceinline__ uint2 pack4(float a, float b, float c, float d) {
  union { unsigned short h[4]; uint2 u; } t;
  t.h[0] = f2bf(a); t.h[1] = f2bf(b); t.h[2] = f2bf(c); t.h[3] = f2bf(d);
  return t.u;
}

static __device__ __forceinline__ s16x8 cvt8(float4 a, float4 b) {
  union { unsigned short h[8]; s16x8 v; } t;
  t.h[0] = f2bf(a.x); t.h[1] = f2bf(a.y); t.h[2] = f2bf(a.z); t.h[3] = f2bf(a.w);
  t.h[4] = f2bf(b.x); t.h[5] = f2bf(b.y); t.h[6] = f2bf(b.z); t.h[7] = f2bf(b.w);
  return t.v;
}

// ---------------- kernel 0: convert + transpose weights to bf16 (R1-proven) ----------
// wqkvT layout: [m][h][d][c]  -> B-fragment reads are 8 contiguous c
// wpT   layout: [c_out][j]    -> B-fragment reads are 8 contiguous j
__global__ __launch_bounds__(256) void convert_weights(
    const float* __restrict__ Wq, const float* __restrict__ Wk,
    const float* __restrict__ Wv, const float* __restrict__ Wp,
    unsigned short* __restrict__ wqkvT, unsigned short* __restrict__ wpT) {
  int idx = blockIdx.x * 256 + threadIdx.x;
  const int NQKV = 3 * NH * ND * NC;  // 442368
  if (idx < NQKV) {
    int c = idx % NC;
    int d = (idx / NC) % ND;
    int h = (idx / (NC * ND)) % NH;
    int m = idx / (NC * ND * NH);
    const float* W = (m == 0) ? Wq : (m == 1) ? Wk : Wv;
    wqkvT[idx] = f2bf(W[(h * NC + c) * ND + d]);
  } else {
    int j = idx - NQKV;               // 0 .. NC*NC-1
    int cc = j / NC, r = j % NC;      // wpT[cc][r] = Wp[r][cc]
    wpT[j] = f2bf(Wp[r * NC + cc]);
  }
}

// ---------------- kernel 1: fused QKV + causal softmax + PV per (b,h) ----------------
// 512 threads = 8 waves. Phase 1 wave grid: 4M x 2N (wave owns 32 q-rows, half the
// q/k/v cols) -> each B-frag LDS read feeds 2 MFMAs (halves LDS-BW vs R1).
// x A-frags load directly from global (own rows; L2-warm across 6 head-blocks).
// Weights reg-staged (3x s16x8) into stride-72 LDS tile, 1 K=64 chunk per 2 barriers.
// Phases 2/3 (swapped-QK^T lane-local softmax, PV) use wave = 16 q-rows (R2-proven).
// LDS 70656 B -> 2 blocks/CU = 16 waves/CU.
__global__ __launch_bounds__(512, 2) void attn_fused(
    const float* __restrict__ x, const unsigned short* __restrict__ wqkvT,
    unsigned short* __restrict__ O) {
  const int lbid = (blockIdx.x & 7) * 384 + (blockIdx.x >> 3);  // XCD-bijective (3072=8*384)
  const int b = lbid / NH;
  const int h = lbid % NH;
  const int tid = threadIdx.x;
  const int lane = tid & 63;
  const int l15 = lane & 15;
  const int lg = lane >> 4;           // 0..3
  const int wid = tid >> 6;           // 0..7
  const int r0 = wid * 16;            // phase2/3: wave's 16 q-rows
  const int mw = wid & 3;             // phase1: M-tile (32 rows)
  const int nw = wid >> 2;            // phase1: N-half (32 of 64 cols)

  __shared__ __align__(16) union {
    unsigned short w[3][64][72];      // phase1 weights tile (27648 B)
    unsigned short qs[128][72];       // phase2 Q (scaled) row-major (18432 B)
    unsigned short pB[128][136];      // phase3 P row-major [q][s] (34816 B)
  } u;
  __shared__ __align__(16) unsigned short ks[128][72];    // K row-major [s][d]
  __shared__ __align__(16) unsigned short vts[64][136];   // V^T [d][s]

  f32x4 acc[3][2][2];                 // [m][nt2][mt]
#pragma unroll
  for (int m = 0; m < 3; ++m)
#pragma unroll
    for (int i = 0; i < 2; ++i)
#pragma unroll
      for (int j = 0; j < 2; ++j) acc[m][i][j] = f32x4{0.f, 0.f, 0.f, 0.f};

  // weight staging: thread covers 16B group (tid&7) of row tid>>3 for each m
  const int wrow = tid >> 3;          // 0..63
  const int wg8 = (tid & 7) * 8;      // 0..56
  const unsigned short* wgp = wqkvT + ((size_t)h * ND + wrow) * NC + wg8;
  const int WM = NH * ND * NC;        // 147456
  s16x8 wa0 = *(const s16x8*)(wgp);
  s16x8 wa1 = *(const s16x8*)(wgp + WM);
  s16x8 wa2 = *(const s16x8*)(wgp + 2 * WM);

  // x A-frag pointers: rows mw*32+l15 and +16, cols lg*8 within each K=64 chunk
  const float* xr0p = x + ((size_t)b * NTOK + mw * 32 + l15) * NC + lg * 8;
  const float* xr1p = xr0p + 16 * NC;

  // ---- phase 1: Q,K,V = x @ W, 6 chunks of K=64, 2 barriers/chunk ----
  for (int kc = 0; kc < 6; ++kc) {
    __syncthreads();                  // readers of previous chunk done
    *(s16x8*)&u.w[0][wrow][wg8] = wa0;
    *(s16x8*)&u.w[1][wrow][wg8] = wa1;
    *(s16x8*)&u.w[2][wrow][wg8] = wa2;
    const float* p0 = xr0p + kc * 64;
    const float* p1 = xr1p + kc * 64;
    float4 f00 = *(const float4*)(p0);      float4 f01 = *(const float4*)(p0 + 4);
    float4 f02 = *(const float4*)(p0 + 32); float4 f03 = *(const float4*)(p0 + 36);
    float4 f10 = *(const float4*)(p1);      float4 f11 = *(const float4*)(p1 + 4);
    float4 f12 = *(const float4*)(p1 + 32); float4 f13 = *(const float4*)(p1 + 36);
    __syncthreads();                  // chunk kc visible
    if (kc < 5) {                     // prefetch next w chunk (consumed next iter)
      wgp += 64;
      wa0 = *(const s16x8*)(wgp);
      wa1 = *(const s16x8*)(wgp + WM);
      wa2 = *(const s16x8*)(wgp + 2 * WM);
    }
    s16x8 a00 = cvt8(f00, f01);       // [mt=0][kd=0]
    s16x8 a01 = cvt8(f02, f03);       // [mt=0][kd=1]
    s16x8 a10 = cvt8(f10, f11);       // [mt=1][kd=0]
    s16x8 a11 = cvt8(f12, f13);       // [mt=1][kd=1]
#pragma unroll
    for (int m = 0; m < 3; ++m)
#pragma unroll
      for (int nt2 = 0; nt2 < 2; ++nt2) {
        const int col = nw * 32 + nt2 * 16 + l15;
        s16x8 b0 = *(const s16x8*)&u.w[m][col][lg * 8];
        acc[m][nt2][0] = MFMA16(a00, b0, acc[m][nt2][0]);
        acc[m][nt2][1] = MFMA16(a10, b0, acc[m][nt2][1]);
        s16x8 b1 = *(const s16x8*)&u.w[m][col][32 + lg * 8];
        acc[m][nt2][0] = MFMA16(a01, b1, acc[m][nt2][0]);
        acc[m][nt2][1] = MFMA16(a11, b1, acc[m][nt2][1]);
      }
  }

  __syncthreads();                    // all w reads done before qs overlays it
  // ---- write Q (scaled), K row-major; V^T packed ----
#pragma unroll
  for (int nt2 = 0; nt2 < 2; ++nt2)
#pragma unroll
    for (int mt = 0; mt < 2; ++mt) {
      const int row = mw * 32 + mt * 16 + 4 * lg;
      const int col = nw * 32 + nt2 * 16 + l15;
#pragma unroll
      for (int r = 0; r < 4; ++r) {
        u.qs[row + r][col] = f2bf(acc[0][nt2][mt][r] * 0.125f);
        ks[row + r][col] = f2bf(acc[1][nt2][mt][r]);
      }
      *(uint2*)&vts[col][row] =
          pack4(acc[2][nt2][mt][0], acc[2][nt2][mt][1],
                acc[2][nt2][mt][2], acc[2][nt2][mt][3]);
    }
  __syncthreads();

  // ---- phase 2: S^T = K @ Q^T (swapped operands -> lane-local score rows) ----
  f32x4 sacc[8];
#pragma unroll
  for (int j = 0; j < 8; ++j) sacc[j] = f32x4{0.f, 0.f, 0.f, 0.f};

#pragma unroll
  for (int kd = 0; kd < 2; ++kd) {
    s16x8 bq = *(const s16x8*)&u.qs[r0 + l15][kd * 32 + lg * 8];
#pragma unroll
    for (int nt = 0; nt < 8; ++nt) {
      if (nt <= wid) {                // causal tile skip (wave-uniform)
        s16x8 ak = *(const s16x8*)&ks[nt * 16 + l15][kd * 32 + lg * 8];
        sacc[nt] = MFMA16(ak, bq, sacc[nt]);
      }
    }
  }

  // in-lane softmax for q = r0 + l15; s = 16*nt + 4*lg + r
  const int q = r0 + l15;
  float mx = -1e30f;
#pragma unroll
  for (int nt = 0; nt < 8; ++nt) {
    if (nt <= wid) {
#pragma unroll
      for (int r = 0; r < 4; ++r) {
        int s = nt * 16 + 4 * lg + r;
        float v = (s <= q) ? sacc[nt][r] : -1e30f;
        sacc[nt][r] = v;
        mx = fmaxf(mx, v);
      }
    }
  }
  mx = fmaxf(mx, __shfl_xor(mx, 16, 64));
  mx = fmaxf(mx, __shfl_xor(mx, 32, 64));
  float sm = 0.f;
#pragma unroll
  for (int nt = 0; nt < 8; ++nt) {
    if (nt <= wid) {
#pragma unroll
      for (int r = 0; r < 4; ++r) {
        float e = __expf(sacc[nt][r] - mx);
        sacc[nt][r] = e;
        sm += e;
      }
    }
  }
  sm += __shfl_xor(sm, 16, 64);
  sm += __shfl_xor(sm, 32, 64);
  float inv = 1.f / sm;

  // ---- stage P row-major [q][s] (overlays qs after barrier) ----
  __syncthreads();
#pragma unroll
  for (int nt = 0; nt < 8; ++nt) {
    uint2 pv;
    if (nt <= wid)
      pv = pack4(sacc[nt][0] * inv, sacc[nt][1] * inv, sacc[nt][2] * inv, sacc[nt][3] * inv);
    else { pv.x = 0u; pv.y = 0u; }
    *(uint2*)&u.pB[r0 + l15][nt * 16 + 4 * lg] = pv;
  }
  __syncthreads();

  // ---- phase 3: O^T = V^T @ P^T ----
  f32x4 oacc[4];
#pragma unroll
  for (int j = 0; j < 4; ++j) oacc[j] = f32x4{0.f, 0.f, 0.f, 0.f};
#pragma unroll
  for (int kd = 0; kd < 4; ++kd) {
    if (kd * 32 <= r0 + 15) {         // s-tiles beyond q_max are all-zero P
      s16x8 bp = *(const s16x8*)&u.pB[r0 + l15][kd * 32 + lg * 8];
#pragma unroll
      for (int dt = 0; dt < 4; ++dt) {
        s16x8 av = *(const s16x8*)&vts[dt * 16 + l15][kd * 32 + lg * 8];
        oacc[dt] = MFMA16(av, bp, oacc[dt]);
      }
    }
  }

  // epilogue: lane holds O[q][d], d = 16*dt + 4*lg + r
  unsigned short* Op = O + ((size_t)(b * NTOK) + r0 + l15) * (NH * ND) + h * ND;
#pragma unroll
  for (int dt = 0; dt < 4; ++dt)
    *(uint2*)&Op[dt * 16 + 4 * lg] =
        pack4(oacc[dt][0], oacc[dt][1], oacc[dt][2], oacc[dt][3]);
}

// ---------------- kernel 2: out = O @ Wp + bp  (M=65536, N=384, K=384) ----------------
__global__ __launch_bounds__(256) void proj_gemm(
    const unsigned short* __restrict__ O, const unsigned short* __restrict__ wpT,
    const float* __restrict__ bp, float* __restrict__ out) {
  const int ntile = blockIdx.x >> 9;   // 0..2
  const int mtile = blockIdx.x & 511;
  const int m0 = mtile * 128, n0 = ntile * 128;
  const int tid = threadIdx.x;
  const int lane = tid & 63;
  const int l15 = lane & 15, lg = lane >> 4;
  const int r0 = (tid >> 6) * 32;

  __shared__ __align__(16) unsigned short as_[128][40];
  __shared__ __align__(16) unsigned short bs_[128][40];

  f32x4 acc[2][8];
#pragma unroll
  for (int i = 0; i < 2; ++i)
#pragma unroll
    for (int j = 0; j < 8; ++j) acc[i][j] = f32x4{0.f, 0.f, 0.f, 0.f};

  const int sr = tid >> 2, sc = (tid & 3) * 8;
  const unsigned short* ag = O + (size_t)(m0 + sr) * NC + sc;
  const unsigned short* bg = wpT + (size_t)(n0 + sr) * NC + sc;
  s16x8 ar0 = *(const s16x8*)ag;
  s16x8 ar1 = *(const s16x8*)(ag + (size_t)64 * NC);
  s16x8 br0 = *(const s16x8*)bg;
  s16x8 br1 = *(const s16x8*)(bg + (size_t)64 * NC);

  for (int kc = 0; kc < 12; ++kc) {
    __syncthreads();
    *(s16x8*)&as_[sr][sc] = ar0;  *(s16x8*)&as_[sr + 64][sc] = ar1;
    *(s16x8*)&bs_[sr][sc] = br0;  *(s16x8*)&bs_[sr + 64][sc] = br1;
    __syncthreads();
    if (kc < 11) {                      // prefetch next K-chunk
      ag += 32; bg += 32;
      ar0 = *(const s16x8*)ag;  ar1 = *(const s16x8*)(ag + (size_t)64 * NC);
      br0 = *(const s16x8*)bg;  br1 = *(const s16x8*)(bg + (size_t)64 * NC);
    }
    s16x8 a0 = *(const s16x8*)&as_[r0 + l15][lg * 8];
    s16x8 a1 = *(const s16x8*)&as_[r0 + 16 + l15][lg * 8];
#pragma unroll
    for (int nt = 0; nt < 8; ++nt) {
      s16x8 bb = *(const s16x8*)&bs_[nt * 16 + l15][lg * 8];
      acc[0][nt] = MFMA16(a0, bb, acc[0][nt]);
      acc[1][nt] = MFMA16(a1, bb, acc[1][nt]);
    }
  }
#pragma unroll
  for (int mt = 0; mt < 2; ++mt)
#pragma unroll
    for (int nt = 0; nt < 8; ++nt) {
      int trow = m0 + r0 + 16 * mt + 4 * lg;
      int col = n0 + nt * 16 + l15;
      float bias = bp[col];
#pragma unroll
      for (int r = 0; r < 4; ++r)
        out[(size_t)(trow + r) * NC + col] = acc[mt][nt][r] + bias;
    }
}

// ---------------- launch ----------------
extern "C" void kernel_launch(void* const* d_in, const int* in_sizes, int n_in,
                              void* d_out, int out_size, void* d_ws, size_t ws_size,
                              hipStream_t stream) {
  const float* x  = (const float*)d_in[0];
  const float* Wq = (const float*)d_in[1];
  const float* Wk = (const float*)d_in[2];
  const float* Wv = (const float*)d_in[3];
  const float* Wp = (const float*)d_in[4];
  const float* bp = (const float*)d_in[5];
  float* out = (float*)d_out;

  char* ws = (char*)d_ws;
  // ws layout: O bf16 [65536][384] @0 (50,331,648 B); wqkvT @50,331,648 (884,736 B);
  //            wpT @51,216,384 (294,912 B). Total ~49.2 MiB.
  unsigned short* O     = (unsigned short*)(ws);
  unsigned short* wqkvT = (unsigned short*)(ws + 50331648);
  unsigned short* wpT   = (unsigned short*)(ws + 51216384);

  convert_weights<<<2304, 256, 0, stream>>>(Wq, Wk, Wv, Wp, wqkvT, wpT);
  attn_fused<<<NB * NH, 512, 0, stream>>>(x, wqkvT, O);
  proj_gemm<<<3 * 512, 256, 0, stream>>>(O, wpT, bp, out);
}

// Round 5
// 362.103 us; speedup vs baseline: 2.3866x; 1.2063x over previous
//
#include <hip/hip_runtime.h>

// Problem constants
#define NB 512
#define NTOK 128
#define NC 384
#define NH 6
#define ND 64

typedef short s16x8 __attribute__((ext_vector_type(8)));
typedef float f32x4 __attribute__((ext_vector_type(4)));

#define MFMA16(a, b, c) __builtin_amdgcn_mfma_f32_16x16x32_bf16((a), (b), (c), 0, 0, 0)

static __device__ __forceinline__ unsigned short f2bf(float f) {
  unsigned int u = __builtin_bit_cast(unsigned int, f);
  u = (u + 0x7FFFu + ((u >> 16) & 1u)) >> 16;   // RNE truncate to bf16
  return (unsigned short)u;
}

static __device__ __forceinline__ uint2 pack4(float a, float b, float c, float d) {
  union { unsigned short h[4]; uint2 u; } t;
  t.h[0] = f2bf(a); t.h[1] = f2bf(b); t.h[2] = f2bf(c); t.h[3] = f2bf(d);
  return t.u;
}

static __device__ __forceinline__ s16x8 cvt8(float4 a, float4 b) {
  union { unsigned short h[8]; s16x8 v; } t;
  t.h[0] = f2bf(a.x); t.h[1] = f2bf(a.y); t.h[2] = f2bf(a.z); t.h[3] = f2bf(a.w);
  t.h[4] = f2bf(b.x); t.h[5] = f2bf(b.y); t.h[6] = f2bf(b.z); t.h[7] = f2bf(b.w);
  return t.v;
}

// async global->LDS, 16B per lane (m97-proven width)
static __device__ __forceinline__ void g2l16(const void* g, void* l) {
  __builtin_amdgcn_global_load_lds(
      (const __attribute__((address_space(1))) unsigned int*)g,
      (__attribute__((address_space(3))) unsigned int*)l, 16, 0, 0);
}

// ---------------- kernel 0: prep (x->bf16 chunk-major, bake w images) -------------
// xbf  [b][kc][t 0..127][32]      : linear 8KB chunk images (64B rows)
// wimg [h][kc][m][d 0..63][32]    : linear 12KB chunk images (64B rows)
// wpT  [cc][r]                    : Wp transposed (proj B-frags read 8 contiguous r)
#define XGRP 3145728   // 512*12*128*4 groups of 8
#define WGRP 55296     // 6*12*3*64*4
__global__ __launch_bounds__(256) void prep(
    const float* __restrict__ x, const float* __restrict__ Wq,
    const float* __restrict__ Wk, const float* __restrict__ Wv,
    const float* __restrict__ Wp,
    unsigned short* __restrict__ xbf, unsigned short* __restrict__ wimg,
    unsigned short* __restrict__ wpT) {
  int g = blockIdx.x * 256 + threadIdx.x;
  if (g < XGRP) {                       // x conversion (coalesced both sides)
    int cg = g & 3;
    int t = (g >> 2) & 127;
    int kc = (g >> 9) % 12;
    int b = g / 6144;
    const float* src = x + (((size_t)b * NTOK + t) * NC + kc * 32 + cg * 8);
    float4 f0 = *(const float4*)src;
    float4 f1 = *(const float4*)(src + 4);
    *(s16x8*)(xbf + (size_t)g * 8) = cvt8(f0, f1);
  } else if (g < XGRP + WGRP) {         // wqkv chunk images
    int gw = g - XGRP;
    int cg = gw & 3;
    int d = (gw >> 2) & 63;
    int rem = gw >> 8;                  // (h*12+kc)*3+m
    int m = rem % 3;
    int hk = rem / 3;
    int kc = hk % 12;
    int h = hk / 12;
    const float* W = (m == 0) ? Wq : (m == 1) ? Wk : Wv;
    const float* s = W + ((size_t)h * NC + kc * 32 + cg * 8) * ND + d;
    union { unsigned short hh[8]; s16x8 v; } o;
#pragma unroll
    for (int j = 0; j < 8; ++j) o.hh[j] = f2bf(s[j * ND]);
    *(s16x8*)(wimg + (size_t)gw * 8) = o.v;
  } else {                              // wpT (18432 groups)
    int j = g - XGRP - WGRP;
    int cc = j / 48;
    int rb = (j % 48) * 8;
    union { unsigned short hh[8]; s16x8 v; } o;
#pragma unroll
    for (int i = 0; i < 8; ++i) o.hh[i] = f2bf(Wp[(size_t)(rb + i) * NC + cc]);
    *(s16x8*)(wpT + (size_t)cc * NC + rb) = o.v;
  }
}

// ---------------- kernel 1: fused QKV + causal softmax + PV per (b,h) -------------
// 512 thr = 8 waves. Phase1: 12 chunks K=32, double-buffered global_load_lds
// (20KB/chunk: xs[128][32] + w[3][64][32], linear 64B rows = min bank cost),
// 1 barrier/chunk, prefetch a full chunk ahead. Wave tile 32 rows x 32 cols x 3m.
// Phases 2/3: R2/R4-proven swapped-QK^T lane-local softmax + PV.
// LDS 58368B -> 2 blocks/CU = 16 waves/CU. VGPR ~96 (cap 128 via (512,2)).
__global__ __launch_bounds__(512, 2) void attn_fused(
    const unsigned short* __restrict__ xbf, const unsigned short* __restrict__ wimg,
    unsigned short* __restrict__ O) {
  const int lbid = (blockIdx.x & 7) * 384 + (blockIdx.x >> 3);  // XCD-bijective
  const int b = lbid / NH;
  const int h = lbid % NH;
  const int tid = threadIdx.x;
  const int lane = tid & 63;
  const int l15 = lane & 15;
  const int lg = lane >> 4;
  const int wid = tid >> 6;
  const int r0 = wid * 16;            // phase2/3 q-rows
  const int mw = wid & 3;             // phase1 M-tile (32 rows)
  const int nw = wid >> 2;            // phase1 N-half (32 cols)

  __shared__ __align__(16) union {
    char dbuf[2][20480];                                      // phase1 chunk dbuf
    struct { unsigned short qs[128][72]; unsigned short ks[128][72]; } qk;
    unsigned short pB[128][136];                              // P row-major [q][s]
  } u;
  __shared__ __align__(16) unsigned short vts[64][136];       // V^T [d][s]

  f32x4 acc[3][2][2];                 // [m][nt2][mt]
#pragma unroll
  for (int m = 0; m < 3; ++m)
#pragma unroll
    for (int i = 0; i < 2; ++i)
#pragma unroll
      for (int j = 0; j < 2; ++j) acc[m][i][j] = f32x4{0.f, 0.f, 0.f, 0.f};

  const char* xsrc = (const char*)xbf + (size_t)b * 98304;    // 12 chunks * 8192B
  const char* wsrc = (const char*)wimg + (size_t)h * 147456;  // 12 chunks * 12288B
  const int o16 = tid * 16;

#define STAGE(kc, pg)                                                   \
  {                                                                     \
    const char* sx = xsrc + (kc) * 8192;                                \
    const char* sw = wsrc + (kc) * 12288;                               \
    char* db = u.dbuf[pg];                                              \
    g2l16(sx + o16, db + o16);                                          \
    g2l16(sw + o16, db + 8192 + o16);                                   \
    if (tid < 256) g2l16(sw + 8192 + o16, db + 16384 + o16);            \
  }

  STAGE(0, 0);
  // ---- phase 1: Q,K,V = x @ W, 12 chunks of K=32, 1 barrier/chunk ----
  for (int kc = 0; kc < 12; ++kc) {
    __syncthreads();                  // drains chunk-kc loads + prev ds_reads
    if (kc < 11) STAGE(kc + 1, (kc + 1) & 1);
    const char* cb = u.dbuf[kc & 1];
    const unsigned short* xs = (const unsigned short*)cb;           // [128][32]
    const unsigned short* wl = (const unsigned short*)(cb + 8192);  // [3][64][32]
    s16x8 a0 = *(const s16x8*)(xs + (mw * 32 + l15) * 32 + lg * 8);
    s16x8 a1 = *(const s16x8*)(xs + (mw * 32 + 16 + l15) * 32 + lg * 8);
#pragma unroll
    for (int m = 0; m < 3; ++m)
#pragma unroll
      for (int nt2 = 0; nt2 < 2; ++nt2) {
        s16x8 bm = *(const s16x8*)(wl + (m * 64 + nw * 32 + nt2 * 16 + l15) * 32 + lg * 8);
        acc[m][nt2][0] = MFMA16(a0, bm, acc[m][nt2][0]);
        acc[m][nt2][1] = MFMA16(a1, bm, acc[m][nt2][1]);
      }
  }

  __syncthreads();                    // last chunk's ds_reads done before overlay
  // ---- write Q (scaled), K row-major; V^T packed ----
#pragma unroll
  for (int nt2 = 0; nt2 < 2; ++nt2)
#pragma unroll
    for (int mt = 0; mt < 2; ++mt) {
      const int row = mw * 32 + mt * 16 + 4 * lg;
      const int col = nw * 32 + nt2 * 16 + l15;
#pragma unroll
      for (int r = 0; r < 4; ++r) {
        u.qk.qs[row + r][col] = f2bf(acc[0][nt2][mt][r] * 0.125f);
        u.qk.ks[row + r][col] = f2bf(acc[1][nt2][mt][r]);
      }
      *(uint2*)&vts[col][row] =
          pack4(acc[2][nt2][mt][0], acc[2][nt2][mt][1],
                acc[2][nt2][mt][2], acc[2][nt2][mt][3]);
    }
  __syncthreads();

  // ---- phase 2: S^T = K @ Q^T (swapped operands -> lane-local score rows) ----
  f32x4 sacc[8];
#pragma unroll
  for (int j = 0; j < 8; ++j) sacc[j] = f32x4{0.f, 0.f, 0.f, 0.f};

#pragma unroll
  for (int kd = 0; kd < 2; ++kd) {
    s16x8 bq = *(const s16x8*)&u.qk.qs[r0 + l15][kd * 32 + lg * 8];
#pragma unroll
    for (int nt = 0; nt < 8; ++nt) {
      if (nt <= wid) {                // causal tile skip (wave-uniform)
        s16x8 ak = *(const s16x8*)&u.qk.ks[nt * 16 + l15][kd * 32 + lg * 8];
        sacc[nt] = MFMA16(ak, bq, sacc[nt]);
      }
    }
  }

  // in-lane softmax for q = r0 + l15; s = 16*nt + 4*lg + r
  const int q = r0 + l15;
  float mx = -1e30f;
#pragma unroll
  for (int nt = 0; nt < 8; ++nt) {
    if (nt <= wid) {
#pragma unroll
      for (int r = 0; r < 4; ++r) {
        int s = nt * 16 + 4 * lg + r;
        float v = (s <= q) ? sacc[nt][r] : -1e30f;
        sacc[nt][r] = v;
        mx = fmaxf(mx, v);
      }
    }
  }
  mx = fmaxf(mx, __shfl_xor(mx, 16, 64));
  mx = fmaxf(mx, __shfl_xor(mx, 32, 64));
  float sm = 0.f;
#pragma unroll
  for (int nt = 0; nt < 8; ++nt) {
    if (nt <= wid) {
#pragma unroll
      for (int r = 0; r < 4; ++r) {
        float e = __expf(sacc[nt][r] - mx);
        sacc[nt][r] = e;
        sm += e;
      }
    }
  }
  sm += __shfl_xor(sm, 16, 64);
  sm += __shfl_xor(sm, 32, 64);
  float inv = 1.f / sm;

  // ---- stage P row-major [q][s] (overlays qs/ks after barrier) ----
  __syncthreads();
#pragma unroll
  for (int nt = 0; nt < 8; ++nt) {
    uint2 pv;
    if (nt <= wid)
      pv = pack4(sacc[nt][0] * inv, sacc[nt][1] * inv, sacc[nt][2] * inv, sacc[nt][3] * inv);
    else { pv.x = 0u; pv.y = 0u; }
    *(uint2*)&u.pB[r0 + l15][nt * 16 + 4 * lg] = pv;
  }
  __syncthreads();

  // ---- phase 3: O^T = V^T @ P^T ----
  f32x4 oacc[4];
#pragma unroll
  for (int j = 0; j < 4; ++j) oacc[j] = f32x4{0.f, 0.f, 0.f, 0.f};
#pragma unroll
  for (int kd = 0; kd < 4; ++kd) {
    if (kd * 32 <= r0 + 15) {         // s-tiles beyond q_max are all-zero P
      s16x8 bp = *(const s16x8*)&u.pB[r0 + l15][kd * 32 + lg * 8];
#pragma unroll
      for (int dt = 0; dt < 4; ++dt) {
        s16x8 av = *(const s16x8*)&vts[dt * 16 + l15][kd * 32 + lg * 8];
        oacc[dt] = MFMA16(av, bp, oacc[dt]);
      }
    }
  }

  // epilogue: lane holds O[q][d], d = 16*dt + 4*lg + r
  unsigned short* Op = O + ((size_t)(b * NTOK) + r0 + l15) * (NH * ND) + h * ND;
#pragma unroll
  for (int dt = 0; dt < 4; ++dt)
    *(uint2*)&Op[dt * 16 + 4 * lg] =
        pack4(oacc[dt][0], oacc[dt][1], oacc[dt][2], oacc[dt][3]);
}

// ---------------- kernel 2: out = O @ Wp + bp  (M=65536, N=384, K=384) -------------
// 256 thr = 4 waves, 128x128 tile, K=64 chunks via double-buffered global_load_lds.
// Chunk image [2][128][32] (64B rows -> min bank cost). LDS 64KB -> 2 blocks/CU.
__global__ __launch_bounds__(256, 2) void proj_gemm(
    const unsigned short* __restrict__ O, const unsigned short* __restrict__ wpT,
    const float* __restrict__ bp, float* __restrict__ out) {
  const int ntile = blockIdx.x >> 9;   // 0..2
  const int mtile = blockIdx.x & 511;
  const int m0 = mtile * 128, n0 = ntile * 128;
  const int tid = threadIdx.x;
  const int lane = tid & 63;
  const int l15 = lane & 15, lg = lane >> 4;
  const int r0 = (tid >> 6) * 32;

  __shared__ __align__(16) char db[2][32768];   // A img 16KB + B img 16KB

  f32x4 acc[2][8];
#pragma unroll
  for (int i = 0; i < 2; ++i)
#pragma unroll
    for (int j = 0; j < 8; ++j) acc[i][j] = f32x4{0.f, 0.f, 0.f, 0.f};

  const char* Ab = (const char*)O + (size_t)m0 * (NC * 2);
  const char* Bb = (const char*)wpT + (size_t)n0 * (NC * 2);

  // dest byte d in a 16KB image: kd=d>>13, row=(d>>6)&127, cg=(d>>4)&3
  // src byte = base + (row*384 + kc*64 + kd*32 + cg*8)*2
#define PSTAGE(kc, pg)                                                       \
  {                                                                          \
    char* dd = db[pg];                                                       \
    _Pragma("unroll")                                                        \
    for (int i = 0; i < 4; ++i) {                                            \
      int d = i * 4096 + tid * 16;                                           \
      int kd = d >> 13, row = (d >> 6) & 127, cg = (d >> 4) & 3;             \
      size_t so = ((size_t)row * NC + (kc) * 64 + kd * 32 + cg * 8) * 2;     \
      g2l16(Ab + so, dd + d);                                                \
      g2l16(Bb + so, dd + 16384 + d);                                        \
    }                                                                        \
  }

  PSTAGE(0, 0);
  for (int kc = 0; kc < 6; ++kc) {
    __syncthreads();
    if (kc < 5) PSTAGE(kc + 1, (kc + 1) & 1);
    const unsigned short* A = (const unsigned short*)db[kc & 1];
    const unsigned short* B = (const unsigned short*)(db[kc & 1] + 16384);
#pragma unroll
    for (int kd = 0; kd < 2; ++kd) {
      const unsigned short* Ak = A + kd * 4096;
      const unsigned short* Bk = B + kd * 4096;
      s16x8 a0 = *(const s16x8*)(Ak + (r0 + l15) * 32 + lg * 8);
      s16x8 a1 = *(const s16x8*)(Ak + (r0 + 16 + l15) * 32 + lg * 8);
#pragma unroll
      for (int nt = 0; nt < 8; ++nt) {
        s16x8 bb = *(const s16x8*)(Bk + (nt * 16 + l15) * 32 + lg * 8);
        acc[0][nt] = MFMA16(a0, bb, acc[0][nt]);
        acc[1][nt] = MFMA16(a1, bb, acc[1][nt]);
      }
    }
  }
#pragma unroll
  for (int mt = 0; mt < 2; ++mt)
#pragma unroll
    for (int nt = 0; nt < 8; ++nt) {
      int trow = m0 + r0 + 16 * mt + 4 * lg;
      int col = n0 + nt * 16 + l15;
      float bias = bp[col];
#pragma unroll
      for (int r = 0; r < 4; ++r)
        out[(size_t)(trow + r) * NC + col] = acc[mt][nt][r] + bias;
    }
}

// ---------------- launch ----------------
extern "C" void kernel_launch(void* const* d_in, const int* in_sizes, int n_in,
                              void* d_out, int out_size, void* d_ws, size_t ws_size,
                              hipStream_t stream) {
  const float* x  = (const float*)d_in[0];
  const float* Wq = (const float*)d_in[1];
  const float* Wk = (const float*)d_in[2];
  const float* Wv = (const float*)d_in[3];
  const float* Wp = (const float*)d_in[4];
  const float* bp = (const float*)d_in[5];
  float* out = (float*)d_out;

  char* ws = (char*)d_ws;
  // ws: O bf16 [65536][384] @0 (50,331,648 B); wimg @50,331,648 (884,736 B);
  //     wpT @51,216,384 (294,912 B). Total ~49.2 MiB (same as proven R1/R4 layout).
  // xbf (50,331,648 B) lives in d_out's storage: dead before proj overwrites out.
  unsigned short* O    = (unsigned short*)(ws);
  unsigned short* wimg = (unsigned short*)(ws + 50331648);
  unsigned short* wpT  = (unsigned short*)(ws + 51216384);
  unsigned short* xbf  = (unsigned short*)d_out;

  prep<<<12576, 256, 0, stream>>>(x, Wq, Wk, Wv, Wp, xbf, wimg, wpT);
  attn_fused<<<NB * NH, 512, 0, stream>>>(xbf, wimg, O);
  proj_gemm<<<3 * 512, 256, 0, stream>>>(O, wpT, bp, out);
}

// Round 6
// 354.490 us; speedup vs baseline: 2.4379x; 1.0215x over previous
//
#include <hip/hip_runtime.h>

// Problem constants
#define NB 512
#define NTOK 128
#define NC 384
#define NH 6
#define ND 64

typedef short s16x8 __attribute__((ext_vector_type(8)));
typedef float f32x4 __attribute__((ext_vector_type(4)));

#define MFMA16(a, b, c) __builtin_amdgcn_mfma_f32_16x16x32_bf16((a), (b), (c), 0, 0, 0)

static __device__ __forceinline__ unsigned short f2bf(float f) {
  unsigned int u = __builtin_bit_cast(unsigned int, f);
  u = (u + 0x7FFFu + ((u >> 16) & 1u)) >> 16;   // RNE truncate to bf16
  return (unsigned short)u;
}

static __device__ __forceinline__ uint2 pack4(float a, float b, float c, float d) {
  union { unsigned short h[4]; uint2 u; } t;
  t.h[0] = f2bf(a); t.h[1] = f2bf(b); t.h[2] = f2bf(c); t.h[3] = f2bf(d);
  return t.u;
}

static __device__ __forceinline__ s16x8 cvt8(float4 a, float4 b) {
  union { unsigned short h[8]; s16x8 v; } t;
  t.h[0] = f2bf(a.x); t.h[1] = f2bf(a.y); t.h[2] = f2bf(a.z); t.h[3] = f2bf(a.w);
  t.h[4] = f2bf(b.x); t.h[5] = f2bf(b.y); t.h[6] = f2bf(b.z); t.h[7] = f2bf(b.w);
  return t.v;
}

// async global->LDS, 16B per lane (m97-proven width)
static __device__ __forceinline__ void g2l16(const void* g, void* l) {
  __builtin_amdgcn_global_load_lds(
      (const __attribute__((address_space(1))) unsigned int*)g,
      (__attribute__((address_space(3))) unsigned int*)l, 16, 0, 0);
}

#define FENCE() asm volatile("" ::: "memory")

// ---------------- kernel 0: prep (x->bf16 chunk images, bake w images) -------------
// All images are 64B-row chunk images with SOURCE-SIDE XOR swizzle: slot group
// cg of row r holds logical k-group (cg ^ (r&3)). Readers XOR the same way ->
// ds_read_b128 bank touches uniform 8/bank (vs 16 for linear).
// xbf  [b][kc 0..11][t 0..127][4x16B]   8KB chunks
// wimg [h][kc 0..11][m][d 0..63][4x16B] 12KB chunks
// wpT  [cc][r] = Wp[r][cc]              (proj stages with its own source swizzle)
#define XGRP 3145728   // 512*12*128*4
#define WGRP 55296     // 6*12*3*64*4
__global__ __launch_bounds__(256) void prep(
    const float* __restrict__ x, const float* __restrict__ Wq,
    const float* __restrict__ Wk, const float* __restrict__ Wv,
    const float* __restrict__ Wp,
    unsigned short* __restrict__ xbf, unsigned short* __restrict__ wimg,
    unsigned short* __restrict__ wpT) {
  int g = blockIdx.x * 256 + threadIdx.x;
  if (g < XGRP) {                       // x conversion (swizzle-baked)
    int cg = g & 3;
    int t = (g >> 2) & 127;
    int kc = (g >> 9) % 12;
    int b = g / 6144;
    int gl = cg ^ (t & 3);              // logical group stored in slot cg
    const float* src = x + (((size_t)b * NTOK + t) * NC + kc * 32 + gl * 8);
    float4 f0 = *(const float4*)src;
    float4 f1 = *(const float4*)(src + 4);
    *(s16x8*)(xbf + (size_t)g * 8) = cvt8(f0, f1);
  } else if (g < XGRP + WGRP) {         // wqkv chunk images (swizzle-baked)
    int gw = g - XGRP;
    int cg = gw & 3;
    int d = (gw >> 2) & 63;
    int rem = gw >> 8;                  // (h*12+kc)*3+m
    int m = rem % 3;
    int hk = rem / 3;
    int kc = hk % 12;
    int h = hk / 12;
    const float* W = (m == 0) ? Wq : (m == 1) ? Wk : Wv;
    int gl = cg ^ (d & 3);
    const float* s = W + ((size_t)h * NC + kc * 32 + gl * 8) * ND + d;
    union { unsigned short hh[8]; s16x8 v; } o;
#pragma unroll
    for (int j = 0; j < 8; ++j) o.hh[j] = f2bf(s[j * ND]);
    *(s16x8*)(wimg + (size_t)gw * 8) = o.v;
  } else {                              // wpT (18432 groups)
    int j = g - XGRP - WGRP;
    int cc = j / 48;
    int rb = (j % 48) * 8;
    union { unsigned short hh[8]; s16x8 v; } o;
#pragma unroll
    for (int i = 0; i < 8; ++i) o.hh[i] = f2bf(Wp[(size_t)(rb + i) * NC + cc]);
    *(s16x8*)(wpT + (size_t)cc * NC + rb) = o.v;
  }
}

// ---------------- kernel 1: fused QKV + causal softmax + PV per (b,h) -------------
// 512 thr = 8 waves. Phase1: 12 chunks K=32, 3-buffer global_load_lds pipeline,
// 2 chunks in flight, counted vmcnt (never 0 mid-loop), ONE raw s_barrier/chunk.
// Waves 0-3 issue 3 stage-loads/chunk, waves 4-7 issue 2 -> per-wave vmcnt(3)/(2).
// Swizzled images: reader XORs 16B-group with (row&3). Phases 2/3: proven
// swapped-QK^T lane-local softmax + PV. LDS 78848B -> 2 blocks/CU.
__global__ __launch_bounds__(512, 2) void attn_fused(
    const unsigned short* __restrict__ xbf, const unsigned short* __restrict__ wimg,
    unsigned short* __restrict__ O) {
  const int lbid = (blockIdx.x & 7) * 384 + (blockIdx.x >> 3);  // XCD-bijective
  const int b = lbid / NH;
  const int h = lbid % NH;
  const int tid = threadIdx.x;
  const int lane = tid & 63;
  const int l15 = lane & 15;
  const int lg = lane >> 4;
  const int wid = tid >> 6;
  const int r0 = wid * 16;            // phase2/3 q-rows
  const int mw = wid & 3;             // phase1 M-tile (32 rows)
  const int nw = wid >> 2;            // phase1 N-half (32 cols)
  const int xswz = (lg ^ (l15 & 3)) * 8;  // swizzled 16B-group (in shorts)

  __shared__ __align__(16) union {
    char dbuf[3][20480];                                      // phase1 pipeline
    struct { unsigned short qs[128][72]; unsigned short ks[128][72]; } qk;
    unsigned short pB[128][136];                              // P row-major [q][s]
  } u;
  __shared__ __align__(16) unsigned short vts[64][136];       // V^T [d][s]

  f32x4 acc[3][2][2];                 // [m][nt2][mt]
#pragma unroll
  for (int m = 0; m < 3; ++m)
#pragma unroll
    for (int i = 0; i < 2; ++i)
#pragma unroll
      for (int j = 0; j < 2; ++j) acc[m][i][j] = f32x4{0.f, 0.f, 0.f, 0.f};

  const char* xsrc = (const char*)xbf + (size_t)b * 98304;    // 12 * 8192B
  const char* wsrc = (const char*)wimg + (size_t)h * 147456;  // 12 * 12288B
  const int o16 = tid * 16;

#define STAGE(kc)                                                       \
  {                                                                     \
    const char* sx = xsrc + (kc) * 8192;                                \
    const char* sw = wsrc + (kc) * 12288;                               \
    char* db = u.dbuf[(kc) % 3];                                        \
    g2l16(sx + o16, db + o16);                                          \
    g2l16(sw + o16, db + 8192 + o16);                                   \
    if (tid < 256) g2l16(sw + 8192 + o16, db + 16384 + o16);            \
  }

  STAGE(0);
  STAGE(1);
  // ---- phase 1: Q,K,V = x @ W, 12 chunks K=32, counted-vmcnt pipeline ----
#pragma unroll
  for (int kc = 0; kc < 12; ++kc) {
    if (kc == 11) { asm volatile("s_waitcnt vmcnt(0)" ::: "memory"); }
    else if (wid < 4) { asm volatile("s_waitcnt vmcnt(3)" ::: "memory"); }
    else { asm volatile("s_waitcnt vmcnt(2)" ::: "memory"); }
    __builtin_amdgcn_s_barrier();     // all waves' chunk-kc loads landed
    FENCE();
    if (kc < 10) STAGE(kc + 2);       // overwrites buf read at iter kc-1 (freed)
    const char* cb = u.dbuf[kc % 3];
    const unsigned short* xs = (const unsigned short*)cb;           // [128][32]
    const unsigned short* wl = (const unsigned short*)(cb + 8192);  // [3][64][32]
    s16x8 a0 = *(const s16x8*)(xs + (mw * 32 + l15) * 32 + xswz);
    s16x8 a1 = *(const s16x8*)(xs + (mw * 32 + 16 + l15) * 32 + xswz);
    __builtin_amdgcn_s_setprio(1);
#pragma unroll
    for (int m = 0; m < 3; ++m)
#pragma unroll
      for (int nt2 = 0; nt2 < 2; ++nt2) {
        s16x8 bm = *(const s16x8*)(wl + (m * 64 + nw * 32 + nt2 * 16 + l15) * 32 + xswz);
        acc[m][nt2][0] = MFMA16(a0, bm, acc[m][nt2][0]);
        acc[m][nt2][1] = MFMA16(a1, bm, acc[m][nt2][1]);
      }
    __builtin_amdgcn_s_setprio(0);
  }

  __syncthreads();                    // last chunk's reads done before overlay
  // ---- write Q (scaled), K row-major; V^T packed ----
#pragma unroll
  for (int nt2 = 0; nt2 < 2; ++nt2)
#pragma unroll
    for (int mt = 0; mt < 2; ++mt) {
      const int row = mw * 32 + mt * 16 + 4 * lg;
      const int col = nw * 32 + nt2 * 16 + l15;
#pragma unroll
      for (int r = 0; r < 4; ++r) {
        u.qk.qs[row + r][col] = f2bf(acc[0][nt2][mt][r] * 0.125f);
        u.qk.ks[row + r][col] = f2bf(acc[1][nt2][mt][r]);
      }
      *(uint2*)&vts[col][row] =
          pack4(acc[2][nt2][mt][0], acc[2][nt2][mt][1],
                acc[2][nt2][mt][2], acc[2][nt2][mt][3]);
    }
  __syncthreads();

  // ---- phase 2: S^T = K @ Q^T (swapped operands -> lane-local score rows) ----
  f32x4 sacc[8];
#pragma unroll
  for (int j = 0; j < 8; ++j) sacc[j] = f32x4{0.f, 0.f, 0.f, 0.f};

#pragma unroll
  for (int kd = 0; kd < 2; ++kd) {
    s16x8 bq = *(const s16x8*)&u.qk.qs[r0 + l15][kd * 32 + lg * 8];
#pragma unroll
    for (int nt = 0; nt < 8; ++nt) {
      if (nt <= wid) {                // causal tile skip (wave-uniform)
        s16x8 ak = *(const s16x8*)&u.qk.ks[nt * 16 + l15][kd * 32 + lg * 8];
        sacc[nt] = MFMA16(ak, bq, sacc[nt]);
      }
    }
  }

  // in-lane softmax for q = r0 + l15; s = 16*nt + 4*lg + r
  const int q = r0 + l15;
  float mx = -1e30f;
#pragma unroll
  for (int nt = 0; nt < 8; ++nt) {
    if (nt <= wid) {
#pragma unroll
      for (int r = 0; r < 4; ++r) {
        int s = nt * 16 + 4 * lg + r;
        float v = (s <= q) ? sacc[nt][r] : -1e30f;
        sacc[nt][r] = v;
        mx = fmaxf(mx, v);
      }
    }
  }
  mx = fmaxf(mx, __shfl_xor(mx, 16, 64));
  mx = fmaxf(mx, __shfl_xor(mx, 32, 64));
  float sm = 0.f;
#pragma unroll
  for (int nt = 0; nt < 8; ++nt) {
    if (nt <= wid) {
#pragma unroll
      for (int r = 0; r < 4; ++r) {
        float e = __expf(sacc[nt][r] - mx);
        sacc[nt][r] = e;
        sm += e;
      }
    }
  }
  sm += __shfl_xor(sm, 16, 64);
  sm += __shfl_xor(sm, 32, 64);
  float inv = 1.f / sm;

  // ---- stage P row-major [q][s] (overlays qs/ks after barrier) ----
  __syncthreads();
#pragma unroll
  for (int nt = 0; nt < 8; ++nt) {
    uint2 pv;
    if (nt <= wid)
      pv = pack4(sacc[nt][0] * inv, sacc[nt][1] * inv, sacc[nt][2] * inv, sacc[nt][3] * inv);
    else { pv.x = 0u; pv.y = 0u; }
    *(uint2*)&u.pB[r0 + l15][nt * 16 + 4 * lg] = pv;
  }
  __syncthreads();

  // ---- phase 3: O^T = V^T @ P^T ----
  f32x4 oacc[4];
#pragma unroll
  for (int j = 0; j < 4; ++j) oacc[j] = f32x4{0.f, 0.f, 0.f, 0.f};
#pragma unroll
  for (int kd = 0; kd < 4; ++kd) {
    if (kd * 32 <= r0 + 15) {         // s-tiles beyond q_max are all-zero P
      s16x8 bp = *(const s16x8*)&u.pB[r0 + l15][kd * 32 + lg * 8];
#pragma unroll
      for (int dt = 0; dt < 4; ++dt) {
        s16x8 av = *(const s16x8*)&vts[dt * 16 + l15][kd * 32 + lg * 8];
        oacc[dt] = MFMA16(av, bp, oacc[dt]);
      }
    }
  }

  // epilogue: lane holds O[q][d], d = 16*dt + 4*lg + r
  unsigned short* Op = O + ((size_t)(b * NTOK) + r0 + l15) * (NH * ND) + h * ND;
#pragma unroll
  for (int dt = 0; dt < 4; ++dt)
    *(uint2*)&Op[dt * 16 + 4 * lg] =
        pack4(oacc[dt][0], oacc[dt][1], oacc[dt][2], oacc[dt][3]);
}

// ---------------- kernel 2: out = O @ Wp + bp  (M=65536, N=384, K=384) -------------
// 512 thr = 8 waves (4M x 2N), tile 256x128, 12 chunks K=32 double-buffered
// global_load_lds (source-XOR-swizzled), 1 barrier/chunk, 16 MFMA/wave/chunk.
// LDS 49152B -> 2 blocks/CU = 16 waves/CU.
__global__ __launch_bounds__(512, 2) void proj_gemm(
    const unsigned short* __restrict__ O, const unsigned short* __restrict__ wpT,
    const float* __restrict__ bp, float* __restrict__ out) {
  const int lb = (blockIdx.x & 7) * 96 + (blockIdx.x >> 3);   // XCD-bijective (768=8*96)
  const int nt3 = lb >> 8;            // 0..2
  const int mtile = lb & 255;
  const int m0 = mtile * 256, n0 = nt3 * 128;
  const int tid = threadIdx.x;
  const int lane = tid & 63;
  const int l15 = lane & 15, lg = lane >> 4;
  const int wid = tid >> 6;
  const int mw4 = wid & 3;            // M quarter (64 rows)
  const int nw = wid >> 2;            // N half (64 cols)
  const int xswz = (lg ^ (l15 & 3)) * 8;

  __shared__ __align__(16) char db[2][24576];   // A img 16KB + B img 8KB

  f32x4 acc[4][4];
#pragma unroll
  for (int i = 0; i < 4; ++i)
#pragma unroll
    for (int j = 0; j < 4; ++j) acc[i][j] = f32x4{0.f, 0.f, 0.f, 0.f};

  const char* Ab = (const char*)O + (size_t)m0 * (NC * 2);
  const char* Bb = (const char*)wpT + (size_t)n0 * (NC * 2);

  // A slots: s = tid + i*512 (i=0,1) -> row s>>2, group s&3 (source-XOR-swizzled)
  // B slots: s = tid           -> row s>>2, group s&3
#define PSTAGE(kc, pg)                                                        \
  {                                                                           \
    char* dd = db[pg];                                                        \
    _Pragma("unroll")                                                         \
    for (int i = 0; i < 2; ++i) {                                             \
      int s = tid + i * 512;                                                  \
      int r = s >> 2, cg = s & 3;                                             \
      size_t so = ((size_t)r * NC + (kc) * 32 + ((cg ^ (r & 3)) * 8)) * 2;    \
      g2l16(Ab + so, dd + s * 16);                                            \
    }                                                                         \
    {                                                                         \
      int r = tid >> 2, cg = tid & 3;                                         \
      size_t so = ((size_t)r * NC + (kc) * 32 + ((cg ^ (r & 3)) * 8)) * 2;    \
      g2l16(Bb + so, dd + 16384 + tid * 16);                                  \
    }                                                                         \
  }

  PSTAGE(0, 0);
  for (int kc = 0; kc < 12; ++kc) {
    __syncthreads();                  // drains chunk-kc loads
    if (kc < 11) PSTAGE(kc + 1, (kc + 1) & 1);
    const unsigned short* A = (const unsigned short*)db[kc & 1];        // [256][32]
    const unsigned short* B = (const unsigned short*)(db[kc & 1] + 16384); // [128][32]
    s16x8 af[4], bf[4];
#pragma unroll
    for (int mt = 0; mt < 4; ++mt)
      af[mt] = *(const s16x8*)(A + (mw4 * 64 + mt * 16 + l15) * 32 + xswz);
#pragma unroll
    for (int nt = 0; nt < 4; ++nt)
      bf[nt] = *(const s16x8*)(B + (nw * 64 + nt * 16 + l15) * 32 + xswz);
    __builtin_amdgcn_s_setprio(1);
#pragma unroll
    for (int mt = 0; mt < 4; ++mt)
#pragma unroll
      for (int nt = 0; nt < 4; ++nt)
        acc[mt][nt] = MFMA16(af[mt], bf[nt], acc[mt][nt]);
    __builtin_amdgcn_s_setprio(0);
  }
#pragma unroll
  for (int mt = 0; mt < 4; ++mt)
#pragma unroll
    for (int nt = 0; nt < 4; ++nt) {
      int trow = m0 + mw4 * 64 + mt * 16 + 4 * lg;
      int col = n0 + nw * 64 + nt * 16 + l15;
      float bias = bp[col];
#pragma unroll
      for (int r = 0; r < 4; ++r)
        out[(size_t)(trow + r) * NC + col] = acc[mt][nt][r] + bias;
    }
}

// ---------------- launch ----------------
extern "C" void kernel_launch(void* const* d_in, const int* in_sizes, int n_in,
                              void* d_out, int out_size, void* d_ws, size_t ws_size,
                              hipStream_t stream) {
  const float* x  = (const float*)d_in[0];
  const float* Wq = (const float*)d_in[1];
  const float* Wk = (const float*)d_in[2];
  const float* Wv = (const float*)d_in[3];
  const float* Wp = (const float*)d_in[4];
  const float* bp = (const float*)d_in[5];
  float* out = (float*)d_out;

  char* ws = (char*)d_ws;
  // ws: O bf16 [65536][384] @0 (50,331,648 B); wimg @50,331,648 (884,736 B);
  //     wpT @51,216,384 (294,912 B).
  // xbf (50,331,648 B) lives in d_out's storage: dead before proj overwrites out.
  unsigned short* O    = (unsigned short*)(ws);
  unsigned short* wimg = (unsigned short*)(ws + 50331648);
  unsigned short* wpT  = (unsigned short*)(ws + 51216384);
  unsigned short* xbf  = (unsigned short*)d_out;

  prep<<<12576, 256, 0, stream>>>(x, Wq, Wk, Wv, Wp, xbf, wimg, wpT);
  attn_fused<<<NB * NH, 512, 0, stream>>>(xbf, wimg, O);
  proj_gemm<<<768, 512, 0, stream>>>(O, wpT, bp, out);
}